// Round 5
// baseline (2841.966 us; speedup 1.0000x reference)
//
#include <hip/hip_runtime.h>
#include <hip/hip_bf16.h>

// Problem constants
#define NB 64    // batch
#define TT 512   // timesteps
#define HH 512   // hidden
#define DD 512   // input dim

typedef __attribute__((ext_vector_type(8))) __bf16 bf16x8;
typedef __attribute__((ext_vector_type(4))) float f32x4;

__device__ __forceinline__ unsigned short f2bf_rn(float f) {
    union { float f; unsigned u; } v; v.f = f;
    unsigned r = v.u + 0x7FFFu + ((v.u >> 16) & 1u);
    return (unsigned short)(r >> 16);
}
__device__ __forceinline__ float bf2f(unsigned short s) {
    union { unsigned u; float f; } v; v.u = ((unsigned)s) << 16;
    return v.f;
}

// ---------------------------------------------------------------------------
// Kernel 1: Wt[n][k]   = bf16_hi(Wx[k][n]),  Wt[n][512+k] = bf16_lo(Wx[k][n])
// ---------------------------------------------------------------------------
__global__ __launch_bounds__(256) void wt_kernel(const float* __restrict__ Wx,
                                                 unsigned short* __restrict__ Wt) {
    const int bk = blockIdx.x >> 3, bn = blockIdx.x & 7;
    const int k0 = bk * 64, n0 = bn * 64;
    __shared__ float tile[64][65];
    const int t = threadIdx.x;
    const int kr = t >> 2, seg = t & 3;
    const float4* src = (const float4*)&Wx[(k0 + kr) * HH + n0 + seg * 16];
    float4 a = src[0], b = src[1], c = src[2], d = src[3];
    float vv[16];
    *(float4*)&vv[0] = a; *(float4*)&vv[4] = b; *(float4*)&vv[8] = c; *(float4*)&vv[12] = d;
#pragma unroll
    for (int q = 0; q < 16; ++q) tile[kr][seg * 16 + q] = vv[q];
    __syncthreads();
    const int nr = t >> 2;
    unsigned hu[8], lu[8];
#pragma unroll
    for (int i = 0; i < 8; ++i) {
        float f0 = tile[seg * 16 + 2 * i + 0][nr];
        float f1 = tile[seg * 16 + 2 * i + 1][nr];
        unsigned short h0 = f2bf_rn(f0); unsigned short l0 = f2bf_rn(f0 - bf2f(h0));
        unsigned short h1 = f2bf_rn(f1); unsigned short l1 = f2bf_rn(f1 - bf2f(h1));
        hu[i] = (unsigned)h0 | ((unsigned)h1 << 16);
        lu[i] = (unsigned)l0 | ((unsigned)l1 << 16);
    }
    unsigned short* dh = &Wt[(n0 + nr) * 1024 + k0 + seg * 16];
    unsigned short* dl = dh + 512;
    ((uint4*)dh)[0] = make_uint4(hu[0], hu[1], hu[2], hu[3]);
    ((uint4*)dh)[1] = make_uint4(hu[4], hu[5], hu[6], hu[7]);
    ((uint4*)dl)[0] = make_uint4(lu[0], lu[1], lu[2], lu[3]);
    ((uint4*)dl)[1] = make_uint4(lu[4], lu[5], lu[6], lu[7]);
}

// ---------------------------------------------------------------------------
// Kernel 2: projection GEMM  out[i][j] = sum_k x[i][k]*Wx[k][j] + b[j]
// split-bf16 (hi*hi + hi*lo + lo*hi) via MFMA. (unchanged — passed)
// ---------------------------------------------------------------------------
#define LDA 72
__global__ __launch_bounds__(256) void proj_kernel(const float* __restrict__ x,
                                                   const unsigned short* __restrict__ Wt,
                                                   const float* __restrict__ bias,
                                                   float* __restrict__ out) {
    __shared__ __align__(16) unsigned short a_hi[64 * LDA];
    __shared__ __align__(16) unsigned short a_lo[64 * LDA];
    __shared__ __align__(16) unsigned short b_hi[64 * LDA];
    __shared__ __align__(16) unsigned short b_lo[64 * LDA];

    const int bx = blockIdx.x;
    const int i0 = (bx >> 3) * 64;
    const int n0 = (bx & 7) * 64;
    const int t = threadIdx.x;
    const int row = t >> 2, seg = t & 3;
    const int lane = t & 63, wid = t >> 6;
    const int wm = (wid >> 1) * 32, wn = (wid & 1) * 32;
    const int fr = lane & 15;

    f32x4 acc00 = {0.f, 0.f, 0.f, 0.f}, acc01 = acc00, acc10 = acc00, acc11 = acc00;

    for (int kc = 0; kc < 8; ++kc) {
        __syncthreads();
        {
            const float4* src = (const float4*)&x[(i0 + row) * DD + kc * 64 + seg * 16];
            float4 a = src[0], b = src[1], c = src[2], d = src[3];
            float vv[16];
            *(float4*)&vv[0] = a; *(float4*)&vv[4] = b; *(float4*)&vv[8] = c; *(float4*)&vv[12] = d;
            unsigned hu[8], lu[8];
#pragma unroll
            for (int i = 0; i < 8; ++i) {
                unsigned short h0 = f2bf_rn(vv[2 * i]); unsigned short l0 = f2bf_rn(vv[2 * i] - bf2f(h0));
                unsigned short h1 = f2bf_rn(vv[2 * i + 1]); unsigned short l1 = f2bf_rn(vv[2 * i + 1] - bf2f(h1));
                hu[i] = (unsigned)h0 | ((unsigned)h1 << 16);
                lu[i] = (unsigned)l0 | ((unsigned)l1 << 16);
            }
            uint4* dh = (uint4*)&a_hi[row * LDA + seg * 16];
            uint4* dl = (uint4*)&a_lo[row * LDA + seg * 16];
            dh[0] = make_uint4(hu[0], hu[1], hu[2], hu[3]);
            dh[1] = make_uint4(hu[4], hu[5], hu[6], hu[7]);
            dl[0] = make_uint4(lu[0], lu[1], lu[2], lu[3]);
            dl[1] = make_uint4(lu[4], lu[5], lu[6], lu[7]);
        }
        {
            const uint4* sh = (const uint4*)&Wt[(n0 + row) * 1024 + kc * 64 + seg * 16];
            const uint4* sl = (const uint4*)&Wt[(n0 + row) * 1024 + 512 + kc * 64 + seg * 16];
            uint4 h0v = sh[0], h1v = sh[1], l0v = sl[0], l1v = sl[1];
            uint4* dh = (uint4*)&b_hi[row * LDA + seg * 16];
            uint4* dl = (uint4*)&b_lo[row * LDA + seg * 16];
            dh[0] = h0v; dh[1] = h1v; dl[0] = l0v; dl[1] = l1v;
        }
        __syncthreads();
#pragma unroll
        for (int s = 0; s < 2; ++s) {
            const int ko = s * 32 + (lane >> 4) * 8;
            bf16x8 ah0 = *(const bf16x8*)&a_hi[(wm + fr) * LDA + ko];
            bf16x8 ah1 = *(const bf16x8*)&a_hi[(wm + 16 + fr) * LDA + ko];
            bf16x8 al0 = *(const bf16x8*)&a_lo[(wm + fr) * LDA + ko];
            bf16x8 al1 = *(const bf16x8*)&a_lo[(wm + 16 + fr) * LDA + ko];
            bf16x8 bh0 = *(const bf16x8*)&b_hi[(wn + fr) * LDA + ko];
            bf16x8 bh1 = *(const bf16x8*)&b_hi[(wn + 16 + fr) * LDA + ko];
            bf16x8 bl0 = *(const bf16x8*)&b_lo[(wn + fr) * LDA + ko];
            bf16x8 bl1 = *(const bf16x8*)&b_lo[(wn + 16 + fr) * LDA + ko];
            acc00 = __builtin_amdgcn_mfma_f32_16x16x32_bf16(ah0, bh0, acc00, 0, 0, 0);
            acc00 = __builtin_amdgcn_mfma_f32_16x16x32_bf16(ah0, bl0, acc00, 0, 0, 0);
            acc00 = __builtin_amdgcn_mfma_f32_16x16x32_bf16(al0, bh0, acc00, 0, 0, 0);
            acc01 = __builtin_amdgcn_mfma_f32_16x16x32_bf16(ah0, bh1, acc01, 0, 0, 0);
            acc01 = __builtin_amdgcn_mfma_f32_16x16x32_bf16(ah0, bl1, acc01, 0, 0, 0);
            acc01 = __builtin_amdgcn_mfma_f32_16x16x32_bf16(al0, bh1, acc01, 0, 0, 0);
            acc10 = __builtin_amdgcn_mfma_f32_16x16x32_bf16(ah1, bh0, acc10, 0, 0, 0);
            acc10 = __builtin_amdgcn_mfma_f32_16x16x32_bf16(ah1, bl0, acc10, 0, 0, 0);
            acc10 = __builtin_amdgcn_mfma_f32_16x16x32_bf16(al1, bh0, acc10, 0, 0, 0);
            acc11 = __builtin_amdgcn_mfma_f32_16x16x32_bf16(ah1, bh1, acc11, 0, 0, 0);
            acc11 = __builtin_amdgcn_mfma_f32_16x16x32_bf16(ah1, bl1, acc11, 0, 0, 0);
            acc11 = __builtin_amdgcn_mfma_f32_16x16x32_bf16(al1, bh1, acc11, 0, 0, 0);
        }
    }
    const float bc0 = bias[n0 + wn + fr];
    const float bc1 = bias[n0 + wn + 16 + fr];
#pragma unroll
    for (int r = 0; r < 4; ++r) {
        int rw0 = i0 + wm + (lane >> 4) * 4 + r;
        int rw1 = rw0 + 16;
        out[rw0 * HH + n0 + wn + fr]      = acc00[r] + bc0;
        out[rw0 * HH + n0 + wn + 16 + fr] = acc01[r] + bc1;
        out[rw1 * HH + n0 + wn + fr]      = acc10[r] + bc0;
        out[rw1 * HH + n0 + wn + 16 + fr] = acc11[r] + bc1;
    }
}

// ---------------------------------------------------------------------------
// Kernel 3: recurrence. grid 256 x 1024 threads, 1 block/CU, all co-resident.
// RESTRUCTURED vs rounds 1-4: block = (batch quad-group gg = b>>4) x
// (col slice s = b&15, 32 cols). Per-thread Wh state is now only 16 floats
// (4 named float4s): thread (jl = tid&31 -> col, kc = tid>>5 -> 16-k chunk)
// computes partials for ALL 4 batch rows with the same weights. This removes
// the allocator's remat incentive (demand ~50 regs < 64 budget), and the
// asm operand barrier below makes remat impossible (values become opaque).
// Rounds 1/3/4 all ran 2.1 ms because the compiler re-loaded the w chunk
// from LLC every step (VGPR_Count 80/60/56 < w size; 32 GB LLC traffic).
// Exchange: 16-block all-to-all per quad-group, parity double-buffered
// tagged by per-(parity,group,slice) flags (same proven protocol).
// ---------------------------------------------------------------------------
__global__ __launch_bounds__(1024)
__attribute__((amdgpu_waves_per_eu(4, 4)))
void rec_kernel(const float* __restrict__ h0,
                const float* __restrict__ Wh,
                float* __restrict__ out,
                float* __restrict__ hbuf,
                int* __restrict__ flags) {
    const int b = blockIdx.x;
    const int gg = b >> 4;          // batch quad-group [0,16)
    const int s  = b & 15;          // col slice [0,16), 32 cols
    const int tid = threadIdx.x;
    const int jl = tid & 31;        // local col [0,32)
    const int kc = tid >> 5;        // k-chunk [0,32), 16 ks each
    const int j  = s * 32 + jl;     // global col
    const int r0 = gg * 4;          // first batch row of the quad

    // ---- one-time: 16 Wh weights into 4 named float4s, pinned via asm ----
    const float* wp = &Wh[(size_t)(kc * 16) * HH + j];
    float4 w0, w1, w2, w3;
#define WLD(v, base)                                                     \
    v.x = wp[(base + 0) * HH]; v.y = wp[(base + 1) * HH];                \
    v.z = wp[(base + 2) * HH]; v.w = wp[(base + 3) * HH];
    WLD(w0, 0) WLD(w1, 4) WLD(w2, 8) WLD(w3, 12)
#undef WLD
    // opaque barrier: results can no longer be rematerialized by re-loading
    asm volatile("" : "+v"(w0.x), "+v"(w0.y), "+v"(w0.z), "+v"(w0.w),
                      "+v"(w1.x), "+v"(w1.y), "+v"(w1.z), "+v"(w1.w),
                      "+v"(w2.x), "+v"(w2.y), "+v"(w2.z), "+v"(w2.w),
                      "+v"(w3.x), "+v"(w3.y), "+v"(w3.z), "+v"(w3.w));

    __shared__ float hs[4][HH];        // h_{t-1} for the 4 rows
    __shared__ float red[4][32][33];   // partials [row][col][kc], padded
    __shared__ float red2[4][4][33];   // stage-A sums [row][quarter][col]

    const int lr = tid >> 5;           // leader row (valid for tid<128)

#pragma unroll 1
    for (int t = 0; t < TT; ++t) {
        const int p  = t & 1;          // publish parity
        const int pp = p ^ 1;          // consume parity (t-1)

        // prefetch xwx for leader threads (in flight across poll/barriers)
        float xw = 0.f;
        if (tid < 128) xw = out[((size_t)(r0 + lr) * TT + t) * HH + j];

        // ---- obtain h_{t-1} (4 rows x 512) into hs ----
        if (t == 0) {
            ((float*)hs)[tid]        = h0[(size_t)r0 * HH + tid];
            ((float*)hs)[tid + 1024] = h0[(size_t)r0 * HH + tid + 1024];
            __syncthreads();
        } else {
            if (tid < 16) {
                int* f = &flags[(pp * 16 + gg) * 16 + tid];
                const int want = t - 1;
                while (__hip_atomic_load(f, __ATOMIC_RELAXED,
                                         __HIP_MEMORY_SCOPE_AGENT) < want) {
                }
            }
            __syncthreads();  // B1: all 16 slice flags observed
            ((float*)hs)[tid] =
                __hip_atomic_load(&hbuf[((size_t)pp * NB + r0) * HH + tid],
                                  __ATOMIC_RELAXED, __HIP_MEMORY_SCOPE_AGENT);
            ((float*)hs)[tid + 1024] =
                __hip_atomic_load(&hbuf[((size_t)pp * NB + r0) * HH + tid + 1024],
                                  __ATOMIC_RELAXED, __HIP_MEMORY_SCOPE_AGENT);
            __syncthreads();  // B2: hs ready
        }

        // ---- matvec partials: 4 rows x 16 ks (w stays in VGPRs) ----
#pragma unroll
        for (int r = 0; r < 4; ++r) {
            const float4* h4 = (const float4*)&hs[r][kc * 16];
            float4 ha = h4[0], hb = h4[1], hc = h4[2], hd = h4[3];
            float p0, p1;
            p0 = w0.x * ha.x;           p1 = w0.y * ha.y;
            p0 = fmaf(w0.z, ha.z, p0);  p1 = fmaf(w0.w, ha.w, p1);
            p0 = fmaf(w1.x, hb.x, p0);  p1 = fmaf(w1.y, hb.y, p1);
            p0 = fmaf(w1.z, hb.z, p0);  p1 = fmaf(w1.w, hb.w, p1);
            p0 = fmaf(w2.x, hc.x, p0);  p1 = fmaf(w2.y, hc.y, p1);
            p0 = fmaf(w2.z, hc.z, p0);  p1 = fmaf(w2.w, hc.w, p1);
            p0 = fmaf(w3.x, hd.x, p0);  p1 = fmaf(w3.y, hd.y, p1);
            p0 = fmaf(w3.z, hd.z, p0);  p1 = fmaf(w3.w, hd.w, p1);
            red[r][jl][kc] = p0 + p1;
        }
        __syncthreads();  // B3: partials ready

        // ---- stage A: 512 threads sum 8 partials each ----
        if (tid < 512) {
            const int rr = tid >> 7, j2 = (tid >> 2) & 31, q = tid & 3;
            float ssum = 0.f;
#pragma unroll
            for (int m = 0; m < 8; ++m) ssum += red[rr][j2][q * 8 + m];
            red2[rr][q][j2] = ssum;
        }
        __syncthreads();  // B3b: stage-A sums ready

        // ---- stage B: 128 leaders finish, tanh, publish ----
        if (tid < 128) {
            float v = xw + red2[lr][0][jl] + red2[lr][1][jl]
                         + red2[lr][2][jl] + red2[lr][3][jl];
            float hn = 1.f - 2.f / (__expf(2.f * v) + 1.f);
            out[((size_t)(r0 + lr) * TT + t) * HH + j] = hn;
            __hip_atomic_store(&hbuf[((size_t)p * NB + r0 + lr) * HH + j], hn,
                               __ATOMIC_RELAXED, __HIP_MEMORY_SCOPE_AGENT);
        }
        __syncthreads();  // B4: vmcnt drain -> h at LLC; LDS reusable
        if (tid == 0)
            __hip_atomic_store(&flags[(p * 16 + gg) * 16 + s], t,
                               __ATOMIC_RELEASE, __HIP_MEMORY_SCOPE_AGENT);
    }
}

// ---------------------------------------------------------------------------
extern "C" void kernel_launch(void* const* d_in, const int* in_sizes, int n_in,
                              void* d_out, int out_size, void* d_ws, size_t ws_size,
                              hipStream_t stream) {
    (void)in_sizes; (void)n_in; (void)out_size; (void)ws_size;
    const float* x  = (const float*)d_in[0];
    const float* h0 = (const float*)d_in[1];
    const float* Wx = (const float*)d_in[2];
    const float* Wh = (const float*)d_in[3];
    const float* bv = (const float*)d_in[4];
    float* out = (float*)d_out;

    // workspace layout (0xAA poison: flag ints are negative -> pollers block)
    int*   flags = (int*)d_ws;                                   // 2*16*16*4 = 2 KiB
    float* hbuf  = (float*)((char*)d_ws + 4096);                 // 2*64*512*4 = 256 KiB
    unsigned short* Wt = (unsigned short*)((char*)d_ws + 4096 + 2 * NB * HH * 4); // 1 MiB

    // 1) split+transpose Wx -> Wt (bf16 hi|lo, B^T layout)
    wt_kernel<<<64, 256, 0, stream>>>(Wx, Wt);

    // 2) projection GEMM: d_out = x @ Wx + b  (split-bf16 MFMA, fp32-accurate)
    proj_kernel<<<(32768 / 64) * (HH / 64), 256, 0, stream>>>(x, Wt, bv, out);

    // 3) sequential recurrence, in-place on d_out
    rec_kernel<<<NB * 4, 1024, 0, stream>>>(h0, Wh, out, hbuf, flags);
}